// Round 6
// baseline (81.638 us; speedup 1.0000x reference)
//
#include <hip/hip_runtime.h>
#include <math.h>

// Problem constants (DigitCapsules)
#define B_   64
#define IC   32
#define D_   288   // ICH*WID*HEI = 8*6*6
#define OC   10
#define OCH  16
#define J_   160   // OC*OCH
#define BJ   10240 // B_*J_

// K1: u_sum[ic][b*160+j] = sum_d u[b,ic,d] * W[ic,d,j]
// grid 512 = bt(16) x ic(32, MINOR -> XCD = ic%8: W slice L2-local to one XCD).
// block 320 = dh(2) x b_sub(4) x j4(40). 16-deep float4 load batches -> only
// 9 serial memory round-trips per wave (was 18). 2 blocks/CU -> 10 waves/CU.
// Also zero-inits k_route's barrier/accumulators (ws poisoned 0xAA each launch).
__global__ __launch_bounds__(320) void k_usum(const float* __restrict__ u,
                                              const float* __restrict__ Wt,
                                              float* __restrict__ US,
                                              float* __restrict__ UDp,
                                              float* __restrict__ nacc,
                                              int* __restrict__ bar) {
    const int ic  = blockIdx.x & 31;
    const int bt  = blockIdx.x >> 5;    // 0..15
    const int tid = threadIdx.x;
    __shared__ float u_lds[4 * D_];     // [b_sub][d]
    __shared__ float part[640];         // dh=1 partials
    __shared__ float ud_part[OC];
    if (tid < OC) ud_part[tid] = 0.f;
    if (blockIdx.x == 0 && tid == 0) {
        nacc[0] = 0.f; nacc[1] = 0.f; nacc[2] = 0.f;
        *bar = 0;                       // ready before k_route (stream order)
    }
    for (int idx = tid; idx < 288; idx += 320) {   // stage u as float4s
        int b_sub = idx / 72;
        int f4    = idx - b_sub * 72;
        int b     = bt * 4 + b_sub;
        ((float4*)u_lds)[idx] =
            ((const float4*)(u + (size_t)(b * IC + ic) * D_))[f4];
    }
    __syncthreads();
    const int j4    = tid % 40;
    const int b_sub = (tid / 40) & 3;
    const int dh    = tid / 160;        // d-half
    const float4* wp = (const float4*)(Wt + (size_t)ic * D_ * J_)
                       + (size_t)dh * 144 * 40 + j4;
    const float*  ur = u_lds + b_sub * D_ + dh * 144;
    float ax = 0.f, ay = 0.f, az = 0.f, aw = 0.f;
    for (int d0 = 0; d0 < 144; d0 += 16) {
        float4 w[16];
        #pragma unroll
        for (int k = 0; k < 16; ++k) w[k] = wp[(d0 + k) * 40];   // 16 in flight
        #pragma unroll
        for (int k = 0; k < 16; ++k) {
            float uv = ur[d0 + k];
            ax += uv * w[k].x; ay += uv * w[k].y;
            az += uv * w[k].z; aw += uv * w[k].w;
        }
    }
    if (dh == 1) ((float4*)part)[tid - 160] = make_float4(ax, ay, az, aw);
    __syncthreads();
    if (dh == 0) {
        float4 p = ((float4*)part)[tid];
        ax += p.x; ay += p.y; az += p.z; aw += p.w;
        ((float4*)(US + (size_t)ic * BJ + (bt * 4 + b_sub) * J_))[j4] =
            make_float4(ax, ay, az, aw);
        float g = ax + ay + az + aw;    // u_dot partial: 4 j's share o = j4>>2
        g += __shfl_xor(g, 1);
        g += __shfl_xor(g, 2);
        if ((tid & 3) == 0) atomicAdd(&ud_part[j4 >> 2], g);
    }
    __syncthreads();
    if (tid < OC) UDp[blockIdx.x * OC + tid] = ud_part[tid];
}

// K2: all 3 routing iterations + squash fused. grid 10 x 1024, one t per thread.
// Barrier: relaxed spin + single acquire (no per-poll cache maintenance);
// release folded into the bar fetch-add (no full __threadfence).
__global__ __launch_bounds__(1024) void k_route(const float* __restrict__ US,
                                                const float* __restrict__ UDp,
                                                float* __restrict__ nacc,
                                                int* __restrict__ bar,
                                                float* __restrict__ out) {
    const int tid = threadIdx.x;
    const int i   = tid & 31;          // in-capsule (tid<320 path)
    const int o   = tid >> 5;          // 0..9     (tid<320 path)
    __shared__ float cij[OC * IC];     // [o][i]
    __shared__ float wred[16];
    __shared__ float nsh;
    float udv = 0.f;
    if (tid < 320) {                   // ud[i][o] = sum over 16 bt tiles (MLP 16)
        #pragma unroll
        for (int bt = 0; bt < 16; ++bt) udv += UDp[(bt * 32 + i) * OC + o];
    }
    const int t  = blockIdx.x * 1024 + tid;   // b*160 + o*16 + e
    const int ot = (t >> 4) % OC;
    float bij = 0.f;
    for (int q = 0; q < 3; ++q) {
        float cs = 0.f;
        if (tid < 320) {
            float m = bij;             // softmax over i (32 aligned lanes)
            m = fmaxf(m, __shfl_xor(m, 16, 32));
            m = fmaxf(m, __shfl_xor(m,  8, 32));
            m = fmaxf(m, __shfl_xor(m,  4, 32));
            m = fmaxf(m, __shfl_xor(m,  2, 32));
            m = fmaxf(m, __shfl_xor(m,  1, 32));
            float e  = __expf(bij - m);
            float se = e;
            se += __shfl_xor(se, 16, 32);
            se += __shfl_xor(se,  8, 32);
            se += __shfl_xor(se,  4, 32);
            se += __shfl_xor(se,  2, 32);
            se += __shfl_xor(se,  1, 32);
            float c = e / se;
            cij[o * IC + i] = c;
            cs = c * udv;              // Σ_i c·ud for this o (butterfly)
            cs += __shfl_xor(cs, 16, 32);
            cs += __shfl_xor(cs,  8, 32);
            cs += __shfl_xor(cs,  4, 32);
            cs += __shfl_xor(cs,  2, 32);
            cs += __shfl_xor(cs,  1, 32);
        }
        __syncthreads();               // cij visible
        float s = 0.f;                 // s_t = Σ_i c[ot][i]·US[i][t], MLP 32
        {
            const float* usp = US + t;
            const float* cp  = cij + ot * IC;
            #pragma unroll
            for (int ii = 0; ii < IC; ++ii) s += cp[ii] * usp[(size_t)ii * BJ];
        }
        float a = fabsf(s);
        #pragma unroll
        for (int off = 32; off; off >>= 1) a += __shfl_down(a, off);
        if ((tid & 63) == 0) wred[tid >> 6] = a;
        __syncthreads();
        if (tid == 0) {
            float blk = 0.f;
            #pragma unroll
            for (int w = 0; w < 16; ++w) blk += wred[w];
            atomicAdd(nacc + q, blk);                       // device-scope add
            __hip_atomic_fetch_add(bar, 1, __ATOMIC_RELEASE,
                                   __HIP_MEMORY_SCOPE_AGENT);
            while (__hip_atomic_load(bar, __ATOMIC_RELAXED,
                                     __HIP_MEMORY_SCOPE_AGENT) < 10 * (q + 1))
                __builtin_amdgcn_s_sleep(1);
            (void)__hip_atomic_load(bar, __ATOMIC_ACQUIRE,  // one acquire
                                    __HIP_MEMORY_SCOPE_AGENT);
            nsh = __hip_atomic_load(nacc + q, __ATOMIC_RELAXED,
                                    __HIP_MEMORY_SCOPE_AGENT);
        }
        __syncthreads();
        const float n  = nsh;
        const float n2 = n * n;
        if (q < 2) {
            if (tid < 320) bij += udv * ((n2 / (1.f + n2)) * (cs / n));
        } else {
            out[t] = (n2 / (1.f + n2)) * (s / n);
        }
    }
}

extern "C" void kernel_launch(void* const* d_in, const int* in_sizes, int n_in,
                              void* d_out, int out_size, void* d_ws, size_t ws_size,
                              hipStream_t stream) {
    (void)in_sizes; (void)n_in; (void)out_size; (void)ws_size;
    const float* u  = (const float*)d_in[0];
    const float* Wt = (const float*)d_in[1];
    float* ws   = (float*)d_ws;
    float* US   = ws;               // 327680 floats: [ic=32][b*160+j]
    float* UDp  = ws + 327680;      // 5120 floats: [block=512][o=10]
    float* nacc = ws + 332800;      // 3 floats
    int*   bar  = (int*)(ws + 332803);

    k_usum<<<dim3(512), dim3(320), 0, stream>>>(u, Wt, US, UDp, nacc, bar);
    k_route<<<dim3(10), dim3(1024), 0, stream>>>(US, UDp, nacc, bar, (float*)d_out);
}